// Round 11
// baseline (161.762 us; speedup 1.0000x reference)
//
#include <hip/hip_runtime.h>
#include <stdint.h>

typedef uint64_t u64;
typedef uint32_t u32;
typedef unsigned short u16;

#define NB    8
#define NQ    4096
#define NKEY  4096
#define CV    64
#define KSEL  16
#define GRD   64
#define NCELL (GRD * GRD)
#define NCHUNK 64            /* 4096/64: lane <-> chunk bijection */
#define CMAX  128
#define PADU  (~(u64)0)

/* d_ws layout: w9(256) + skey(256K) + sidx(64K) + bbox(8K) = 328,960 B
   (R6 proved ws_size >= 524,544) */
#define WS_SKEY  256
#define WS_SIDX  (WS_SKEY + NB * NKEY * 8)
#define WS_BBOX  (WS_SIDX + NB * NKEY * 2)

__device__ __forceinline__ u64 shflxor_u64(u64 v, int m) {
    const u32 lo = __shfl_xor((int)(u32)v, m);
    const u32 hi = __shfl_xor((int)(u32)(v >> 32), m);
    return (((u64)hi) << 32) | lo;
}
__device__ __forceinline__ int mbcnt64(u64 m) {
    return (int)__builtin_amdgcn_mbcnt_hi((u32)(m >> 32),
               __builtin_amdgcn_mbcnt_lo((u32)m, 0));
}
__device__ __forceinline__ int cellof(float x) {
    int c = (int)floorf((x + 4.0f) * 8.0f);
    return c < 0 ? 0 : (c > GRD - 1 ? GRD - 1 : c);
}
__device__ __forceinline__ u32 part1by1(u32 x) {   /* spread low 8 bits */
    x &= 0xFFu;
    x = (x | (x << 4)) & 0x0F0Fu;
    x = (x | (x << 2)) & 0x3333u;
    x = (x | (x << 1)) & 0x5555u;
    return x;
}

/* EXACT smallest-16 SET of 64 lane values -> lanes 0..15 (unspecified order) */
__device__ __forceinline__ u64 top16of64(u64 v, int lane) {
#pragma unroll
    for (int k = 2; k <= 16; k <<= 1) {
#pragma unroll
        for (int j = k >> 1; j > 0; j >>= 1) {
            const u64 p = shflxor_u64(v, j);
            const bool up    = ((lane & k) == 0);
            const bool lower = ((lane & j) == 0);
            const u64 mn = v < p ? v : p, mx = v < p ? p : v;
            v = (lower == up) ? mn : mx;
        }
    }
    {   const u64 p = shflxor_u64(v, 16);
        const u64 mn = v < p ? v : p, mx = v < p ? p : v;
        v = ((lane & 16) == 0) ? mn : mx; }
#pragma unroll
    for (int j = 8; j > 0; j >>= 1) {
        const u64 p = shflxor_u64(v, j);
        const bool lower = ((lane & j) == 0);
        const bool dasc  = ((lane & 32) == 0);
        const u64 mn = v < p ? v : p, mx = v < p ? p : v;
        v = (lower == dasc) ? mn : mx;
    }
    {   const u64 p = shflxor_u64(v, 32);
        const u64 mn = v < p ? v : p, mx = v < p ? p : v;
        v = ((lane & 32) == 0) ? mn : mx; }
    return v;
}

/* ---- fused setup: Morton counting-sort in LDS + chunk bboxes + w9 ---- */
__global__ __launch_bounds__(1024, 1) void k_setup(
    const float* __restrict__ kg,
    const float* __restrict__ qw, const float* __restrict__ qb,
    const float* __restrict__ kw, const float* __restrict__ kb,
    float2* __restrict__ skey_g, u16* __restrict__ sidx_g,
    float4* __restrict__ bbox_g, float* __restrict__ w9)
{
    __shared__ u32    hist[NCELL];     /* counts -> then bump cursors */
    __shared__ float2 skl[NKEY];
    __shared__ u16    sil[NKEY];
    __shared__ u32    wtot[16];

    const int b = blockIdx.x, t = threadIdx.x;
    const int wv = t >> 6, lane = t & 63;

#pragma unroll
    for (int i = 0; i < 4; ++i) hist[t * 4 + i] = 0u;
    __syncthreads();

    float2 kk[4]; int cel[4];
#pragma unroll
    for (int i = 0; i < 4; ++i) {
        const int gid = t + i * 1024;
        kk[i] = ((const float2*)kg)[(size_t)b * NKEY + gid];
        cel[i] = (int)(part1by1((u32)cellof(kk[i].x)) |
                       (part1by1((u32)cellof(kk[i].y)) << 1));
        atomicAdd(&hist[cel[i]], 1u);
    }
    __syncthreads();

    /* hierarchical exclusive scan; hist becomes per-cell start cursors */
    const u32 h0 = hist[4 * t], h1 = hist[4 * t + 1];
    const u32 h2 = hist[4 * t + 2], h3 = hist[4 * t + 3];
    const u32 s = h0 + h1 + h2 + h3;
    u32 inc = s;
#pragma unroll
    for (int off = 1; off < 64; off <<= 1) {
        const u32 p = __shfl_up(inc, off);
        if (lane >= off) inc += p;
    }
    if (lane == 63) wtot[wv] = inc;
    __syncthreads();
    if (wv == 0 && lane < 16) {
        const u32 v = wtot[lane];
        u32 sc = v;
#pragma unroll
        for (int off = 1; off < 16; off <<= 1) {
            const u32 p = __shfl_up(sc, off);
            if (lane >= off) sc += p;
        }
        wtot[lane] = sc - v;
    }
    __syncthreads();
    const u32 base = wtot[wv] + (inc - s);
    hist[4 * t]     = base;
    hist[4 * t + 1] = base + h0;
    hist[4 * t + 2] = base + h0 + h1;
    hist[4 * t + 3] = base + h0 + h1 + h2;
    __syncthreads();

#pragma unroll
    for (int i = 0; i < 4; ++i) {
        const u32 p = atomicAdd(&hist[cel[i]], 1u);
        skl[p] = kk[i];
        sil[p] = (u16)(t + i * 1024);
    }
    __syncthreads();

    float2* skb = skey_g + (size_t)b * NKEY;
    u16*    sib = sidx_g + (size_t)b * NKEY;
#pragma unroll
    for (int i = 0; i < 4; ++i) {
        const int g = t + i * 1024;
        skb[g] = skl[g];
        sib[g] = sil[g];
    }
#pragma unroll
    for (int j = 0; j < 4; ++j) {
        const int ch = wv * 4 + j;
        const float2 kc = skl[ch * 64 + lane];
        float xlo = kc.x, xhi = kc.x, ylo = kc.y, yhi = kc.y;
#pragma unroll
        for (int off = 32; off; off >>= 1) {
            xlo = fminf(xlo, __shfl_xor(xlo, off));
            xhi = fmaxf(xhi, __shfl_xor(xhi, off));
            ylo = fminf(ylo, __shfl_xor(ylo, off));
            yhi = fmaxf(yhi, __shfl_xor(yhi, off));
        }
        if (lane == 0) bbox_g[b * NCHUNK + ch] = make_float4(xlo, ylo, xhi, yhi);
    }

    if (b == 0 && t < 64) {
        const int h = t;
        const float2 a = ((const float2*)qw)[h];
        const float2 c = ((const float2*)kw)[h];
        const float qbh = qb[h], kbh = kb[h];
        float ss[9] = { a.x * c.x, a.y * c.x, qbh * c.x,
                        a.x * c.y, a.y * c.y, qbh * c.y,
                        a.x * kbh, a.y * kbh, qbh * kbh };
#pragma unroll
        for (int i = 0; i < 9; ++i)
#pragma unroll
            for (int off = 32; off; off >>= 1) ss[i] += __shfl_xor(ss[i], off);
        if (h == 0) {
#pragma unroll
            for (int i = 0; i < 9; ++i) w9[i] = ss[i];
        }
    }
}

/* ---- main: 1 wave per query; lane = chunk in the bbox phase ---- */
extern "C" __global__ __launch_bounds__(256, 8) void bev_knn(
    const float* __restrict__ qg, const float* __restrict__ kg,
    const float* __restrict__ vg, const float* __restrict__ w9,
    const float2* __restrict__ skey_g, const u16* __restrict__ sidx_g,
    const float4* __restrict__ bbox_g, float* __restrict__ outg)
{
    __shared__ u64 cand[4][CMAX];                     /* 4 KB */

    const int tid = threadIdx.x, wv = tid >> 6, lane = tid & 63;
    const int gw = blockIdx.x * 4 + wv;
    const int b  = gw >> 12, qi = gw & 4095;

    const float2 qc = ((const float2*)qg)[(size_t)b * NQ + qi];
    const float qx = qc.x, qy = qc.y;
    const float2* sk = skey_g + (size_t)b * NKEY;
    const u16*    si = sidx_g + (size_t)b * NKEY;
    u64* cd = cand[wv];

    /* bbox distance, lane = chunk */
    const float4 bb = bbox_g[b * NCHUNK + lane];
    const float dx = fmaxf(fmaxf(bb.x - qx, qx - bb.z), 0.f);
    const float dy = fmaxf(fmaxf(bb.y - qy, qy - bb.w), 0.f);
    const float bd = fmaf(dx, dx, dy * dy);

    /* nearest chunk */
    float bmn = bd;
#pragma unroll
    for (int off = 32; off; off >>= 1) bmn = fminf(bmn, __shfl_xor(bmn, off));
    const int cn = __builtin_ctzll((unsigned long long)__ballot(bd == bmn));

    /* scan nearest chunk -> exact best-16 so far */
    u64 myv;
    {
        const int pos = cn * 64 + lane;
        const float2 kk = sk[pos];
        const float ddx = qx - kk.x, ddy = qy - kk.y;
        const float d2 = fmaf(ddx, ddx, ddy * ddy);
        myv = (((u64)__float_as_uint(d2)) << 32) | (u32)si[pos];
    }
    myv = top16of64(myv, lane);

    u64 b16;
    {
        u64 m = (lane < KSEL) ? myv : 0;
#pragma unroll
        for (int off = 32; off; off >>= 1) { const u64 p = shflxor_u64(m, off); m = p > m ? p : m; }
        b16 = m;
    }
    float d16f = __uint_as_float((u32)(b16 >> 32));

    /* scan all other chunks that can hold an improver */
    u64 mask = __ballot(bd <= d16f) & ~(1ull << cn);
    int ecnt = 0;
#pragma unroll 1
    while (mask) {
        const int c = __builtin_ctzll((unsigned long long)mask);
        mask &= mask - 1;
        const int pos = c * 64 + lane;
        const float2 kk = sk[pos];
        const float ddx = qx - kk.x, ddy = qy - kk.y;
        const float d2 = fmaf(ddx, ddx, ddy * ddy);
        const u64 pk = (((u64)__float_as_uint(d2)) << 32) | (u32)si[pos];
        const bool acc = pk < b16;
        const u64 mk = __ballot(acc);
        if (mk) {
            const int p = ecnt + mbcnt64(mk);
            if (acc) cd[p] = pk;                      /* p < 64+64 = CMAX */
            ecnt += (int)__popcll(mk);
            if (ecnt >= CMAX - 64) {                  /* flush + tighten */
#pragma unroll 1
                while (ecnt > 0) {
                    const int take = ecnt < 48 ? ecnt : 48;
                    const u64 inv = (lane < KSEL) ? myv
                                  : ((lane - KSEL < take) ? cd[ecnt - take + lane - KSEL] : PADU);
                    myv = top16of64(inv, lane);
                    ecnt -= take;
                }
                u64 m = (lane < KSEL) ? myv : 0;
#pragma unroll
                for (int off = 32; off; off >>= 1) { const u64 p2 = shflxor_u64(m, off); m = p2 > m ? p2 : m; }
                b16 = m; d16f = __uint_as_float((u32)(b16 >> 32));
                mask &= __ballot(bd <= d16f);
            }
        }
    }
#pragma unroll 1
    while (ecnt > 0) {                                /* final flush */
        const int take = ecnt < 48 ? ecnt : 48;
        const u64 inv = (lane < KSEL) ? myv
                      : ((lane - KSEL < take) ? cd[ecnt - take + lane - KSEL] : PADU);
        myv = top16of64(inv, lane);
        ecnt -= take;
    }

    /* epilogue: affine scores, width-16 softmax, V gather (R9-proven) */
    const u32 myidx = (u32)myv;                       /* original idx 0..4095 */
    const float A  = fmaf(qx, w9[0], fmaf(qy, w9[1], w9[2]));
    const float Bb = fmaf(qx, w9[3], fmaf(qy, w9[4], w9[5]));
    const float Cc = fmaf(qx, w9[6], fmaf(qy, w9[7], w9[8]));

    const float2* kp = (const float2*)kg + (size_t)b * NKEY;
    const int sel = (lane < KSEL) ? (int)myidx : 0;
    const float2 kc = kp[sel];
    const float score = fmaf(A, kc.x, fmaf(Bb, kc.y, Cc));
    float mx = score;
#pragma unroll
    for (int off = 8; off; off >>= 1) mx = fmaxf(mx, __shfl_xor(mx, off));
    const float e = __expf(score - mx);
    float sum = e;
#pragma unroll
    for (int off = 8; off; off >>= 1) sum += __shfl_xor(sum, off);
    const float w = e / sum;                          /* valid lanes 0..15 */

    const float* vb = vg + (size_t)b * NKEY * CV;
    float acc = 0.f;
#pragma unroll
    for (int sct = 0; sct < KSEL; ++sct) {
        const u32 id   = (u32)__builtin_amdgcn_readlane((int)myidx, sct);
        const float ws = __uint_as_float(
            (u32)__builtin_amdgcn_readlane((int)__float_as_uint(w), sct));
        acc = fmaf(ws, vb[(size_t)id * CV + lane], acc);
    }
    outg[((size_t)b * NQ + qi) * CV + lane] = acc;
}

extern "C" void kernel_launch(void* const* d_in, const int* in_sizes, int n_in,
                              void* d_out, int out_size, void* d_ws, size_t ws_size,
                              hipStream_t stream) {
    const float* q  = (const float*)d_in[0];
    const float* k  = (const float*)d_in[1];
    const float* v  = (const float*)d_in[2];
    const float* qw = (const float*)d_in[3];
    const float* qb = (const float*)d_in[4];
    const float* kw = (const float*)d_in[5];
    const float* kb = (const float*)d_in[6];
    /* d_in[7] = top_k (always 16; compile-time) */
    float* out = (float*)d_out;

    float*  w9   = (float*)d_ws;
    float2* skey = (float2*)((char*)d_ws + WS_SKEY);
    u16*    sidx = (u16*)((char*)d_ws + WS_SIDX);
    float4* bbox = (float4*)((char*)d_ws + WS_BBOX);

    hipLaunchKernelGGL(k_setup, dim3(NB), dim3(1024), 0, stream,
                       k, qw, qb, kw, kb, skey, sidx, bbox, w9);
    hipLaunchKernelGGL(bev_knn, dim3(NB * NQ / 4), dim3(256), 0, stream,
                       q, k, v, w9, skey, sidx, bbox, out);
}

// Round 12
// 97.583 us; speedup vs baseline: 1.6577x; 1.6577x over previous
//
#include <hip/hip_runtime.h>
#include <stdint.h>

typedef uint64_t u64;
typedef uint32_t u32;
typedef unsigned short u16;

#define NB    8
#define NQ    4096
#define NKEY  4096
#define CV    64
#define KSEL  16
#define NBKT  256
#define BW    0.03125f       /* 8/256 */
#define GLO   -4.0f
#define CMAX  128
#define PADU  (~(u64)0)

/* d_ws: w9 256B | bucket_start 8*257*4 (pad 8448) | sx 256KB | si 64KB = 336,384 B
   (R6 proved ws_size >= 524,544) */
#define WS_BS   256
#define WS_SX   (WS_BS + 8448)
#define WS_SI   (WS_SX + NB * NKEY * 8)

__device__ __forceinline__ u64 shflxor_u64(u64 v, int m) {
    const u32 lo = __shfl_xor((int)(u32)v, m);
    const u32 hi = __shfl_xor((int)(u32)(v >> 32), m);
    return (((u64)hi) << 32) | lo;
}
__device__ __forceinline__ int mbcnt64(u64 m) {
    return (int)__builtin_amdgcn_mbcnt_hi((u32)(m >> 32),
               __builtin_amdgcn_mbcnt_lo((u32)m, 0));
}

/* EXACT smallest-16 SET of 64 lane values -> lanes 0..15 (unspecified order) */
__device__ __forceinline__ u64 top16of64(u64 v, int lane) {
#pragma unroll
    for (int k = 2; k <= 16; k <<= 1) {
#pragma unroll
        for (int j = k >> 1; j > 0; j >>= 1) {
            const u64 p = shflxor_u64(v, j);
            const bool up    = ((lane & k) == 0);
            const bool lower = ((lane & j) == 0);
            const u64 mn = v < p ? v : p, mx = v < p ? p : v;
            v = (lower == up) ? mn : mx;
        }
    }
    {   const u64 p = shflxor_u64(v, 16);
        const u64 mn = v < p ? v : p, mx = v < p ? p : v;
        v = ((lane & 16) == 0) ? mn : mx; }
#pragma unroll
    for (int j = 8; j > 0; j >>= 1) {
        const u64 p = shflxor_u64(v, j);
        const bool lower = ((lane & j) == 0);
        const bool dasc  = ((lane & 32) == 0);
        const u64 mn = v < p ? v : p, mx = v < p ? p : v;
        v = (lower == dasc) ? mn : mx;
    }
    {   const u64 p = shflxor_u64(v, 32);
        const u64 mn = v < p ? v : p, mx = v < p ? p : v;
        v = ((lane & 32) == 0) ? mn : mx; }
    return v;
}

/* ---- setup: per-batch counting sort by 256 x-buckets + bucket_start + w9 ---- */
__global__ __launch_bounds__(1024, 1) void k_setup(
    const float* __restrict__ kg,
    const float* __restrict__ qw, const float* __restrict__ qb,
    const float* __restrict__ kw, const float* __restrict__ kb,
    u32* __restrict__ bs_g, float2* __restrict__ sx_g, u16* __restrict__ si_g,
    float* __restrict__ w9)
{
    __shared__ u32 hist[NBKT];
    __shared__ u32 scn[NBKT];
    __shared__ u32 wtot[4];

    const int b = blockIdx.x, t = threadIdx.x;
    const int wv = t >> 6, lane = t & 63;

    if (t < NBKT) hist[t] = 0u;
    __syncthreads();

    float2 kk[4]; int xb[4];
#pragma unroll
    for (int i = 0; i < 4; ++i) {
        const int gid = t + i * 1024;
        kk[i] = ((const float2*)kg)[(size_t)b * NKEY + gid];
        int bb = (int)floorf((kk[i].x - GLO) * 32.0f);
        xb[i] = bb < 0 ? 0 : (bb > NBKT - 1 ? NBKT - 1 : bb);
        atomicAdd(&hist[xb[i]], 1u);
    }
    __syncthreads();

    u32 v = 0, inc = 0;
    if (t < NBKT) {
        v = hist[t];
        inc = v;
#pragma unroll
        for (int off = 1; off < 64; off <<= 1) {
            const u32 p = __shfl_up(inc, off);
            if (lane >= off) inc += p;
        }
        if (lane == 63) wtot[wv] = inc;
    }
    __syncthreads();
    if (t == 0) {
        u32 a = 0;
#pragma unroll
        for (int i = 0; i < 4; ++i) { const u32 x = wtot[i]; wtot[i] = a; a += x; }
    }
    __syncthreads();
    if (t < NBKT) {
        const u32 st = wtot[t >> 6] + inc - v;      /* exclusive start */
        scn[t] = st;
        bs_g[b * 257 + t] = st;
    }
    if (t == 0) bs_g[b * 257 + NBKT] = NKEY;
    __syncthreads();

#pragma unroll
    for (int i = 0; i < 4; ++i) {
        const u32 p = atomicAdd(&scn[xb[i]], 1u);
        sx_g[(size_t)b * NKEY + p] = kk[i];
        si_g[(size_t)b * NKEY + p] = (u16)(t + i * 1024);
    }

    if (b == 0 && t < 64) {
        const int h = t;
        const float2 a = ((const float2*)qw)[h];
        const float2 c = ((const float2*)kw)[h];
        const float qbh = qb[h], kbh = kb[h];
        float ss[9] = { a.x * c.x, a.y * c.x, qbh * c.x,
                        a.x * c.y, a.y * c.y, qbh * c.y,
                        a.x * kbh, a.y * kbh, qbh * kbh };
#pragma unroll
        for (int i = 0; i < 9; ++i)
#pragma unroll
            for (int off = 32; off; off >>= 1) ss[i] += __shfl_xor(ss[i], off);
        if (h == 0) {
#pragma unroll
            for (int i = 0; i < 9; ++i) w9[i] = ss[i];
        }
    }
}

/* ---- main: 1 wave/query; outward contiguous block scan over x-sorted keys ---- */
extern "C" __global__ __launch_bounds__(256, 8) void bev_knn(
    const float* __restrict__ qg, const float* __restrict__ kg,
    const float* __restrict__ vg, const float* __restrict__ w9,
    const u32* __restrict__ bs_g, const float2* __restrict__ sx_g,
    const u16* __restrict__ si_g, float* __restrict__ outg)
{
    __shared__ u64 cand[4][CMAX];                   /* 4 KB */
    __shared__ u32 bsl[NBKT + 1];

    const int tid = threadIdx.x, wv = tid >> 6, lane = tid & 63;
    const int b  = blockIdx.x >> 10;                /* 1024 blocks per batch */
    const int qi = ((int)(blockIdx.x & 1023)) * 4 + wv;

    for (int i = tid; i < NBKT + 1; i += 256) bsl[i] = bs_g[b * 257 + i];
    __syncthreads();

    const float2 qc = ((const float2*)qg)[(size_t)b * NQ + qi];
    const float qx = qc.x, qy = qc.y;
    const float2* sx = sx_g + (size_t)b * NKEY;
    const u16*    si = si_g + (size_t)b * NKEY;
    u64* cd = cand[wv];

    int qbx = (int)floorf((qx - GLO) * 32.0f);
    qbx = qbx < 0 ? 0 : (qbx > NBKT - 1 ? NBKT - 1 : qbx);
    int c0 = (int)bsl[qbx] - 32;
    c0 = c0 < 0 ? 0 : (c0 > NKEY - 64 ? NKEY - 64 : c0);

    /* initial block -> exact best-16 of those 64 */
    u64 myv;
    {
        const int pos = c0 + lane;
        const float2 kk = sx[pos];
        const float dx = qx - kk.x, dy = qy - kk.y;
        const float d2 = fmaf(dx, dx, dy * dy);
        myv = (((u64)__float_as_uint(d2)) << 32) | (u32)si[pos];
    }
    myv = top16of64(myv, lane);

    u64 b16; float d16f;
    int ecnt = 0;

    auto refresh = [&]() {
        u64 m = (lane < KSEL) ? myv : 0;
#pragma unroll
        for (int off = 32; off; off >>= 1) { const u64 p = shflxor_u64(m, off); m = p > m ? p : m; }
        b16 = m; d16f = __uint_as_float((u32)(b16 >> 32));
    };
    refresh();

    auto flushfn = [&]() {
#pragma unroll 1
        while (ecnt > 0) {
            const int take = ecnt < 48 ? ecnt : 48;
            const u64 inv = (lane < KSEL) ? myv
                          : ((lane - KSEL < take) ? cd[ecnt - take + lane - KSEL] : PADU);
            myv = top16of64(inv, lane);
            ecnt -= take;
        }
        refresh();
    };

    auto doBlock = [&](int base, int lim) {         /* lim - base <= 64 */
        const int pos = base + lane;
        u64 pk = PADU;
        if (pos < lim) {
            const float2 kk = sx[pos];
            const float dx = qx - kk.x, dy = qy - kk.y;
            const float d2 = fmaf(dx, dx, dy * dy);
            pk = (((u64)__float_as_uint(d2)) << 32) | (u32)si[pos];
        }
        const bool acc = pk < b16;
        const u64 mk = __ballot(acc);
        if (mk) {
            const int p = ecnt + mbcnt64(mk);
            if (acc) cd[p] = pk;                    /* p <= 64+63 < CMAX */
            ecnt += (int)__popcll(mk);
            if (ecnt > CMAX - 64) flushfn();
        }
    };

    /* outward scan; bucket-edge bounds prove termination (exact) */
    int L = c0, Rr = c0 + 64;
    int bl = qbx, br = qbx;
    bool goL = (L > 0), goR = (Rr < NKEY);
#pragma unroll 1
    while (goL || goR) {
        if (goR) {
#pragma unroll 1
            while (br < NBKT - 1 && Rr >= (int)bsl[br + 1]) ++br;
            /* unseen right keys: x >= left edge of bucket br (br=0 clamped: -inf) */
            const float edge = (br == 0) ? -1e30f : (GLO + (float)br * BW);
            const float bnd = edge - qx - 1e-4f;
            if (bnd > 0.f && bnd * bnd > d16f) goR = false;
            else {
                const int lim = (Rr + 64 < NKEY) ? Rr + 64 : NKEY;
                doBlock(Rr, lim);
                Rr = lim;
                if (Rr >= NKEY) goR = false;
            }
        }
        if (goL) {
#pragma unroll 1
            while (bl > 0 && (L - 1) < (int)bsl[bl]) --bl;
            /* unseen left keys: x <= right edge of bucket bl (bl=255 clamped: +inf) */
            const float edge = (bl == NBKT - 1) ? 1e30f : (GLO + (float)(bl + 1) * BW);
            const float bnd = qx - edge - 1e-4f;
            if (bnd > 0.f && bnd * bnd > d16f) goL = false;
            else {
                const int base = (L - 64 > 0) ? L - 64 : 0;
                doBlock(base, L);
                L = base;
                if (L <= 0) goL = false;
            }
        }
    }
    flushfn();

    /* epilogue: affine scores, width-16 softmax, V gather (R9-proven) */
    const u32 myidx = (u32)myv;                     /* original idx, lanes 0..15 */
    const float A  = fmaf(qx, w9[0], fmaf(qy, w9[1], w9[2]));
    const float Bb = fmaf(qx, w9[3], fmaf(qy, w9[4], w9[5]));
    const float Cc = fmaf(qx, w9[6], fmaf(qy, w9[7], w9[8]));

    const float2* kp = (const float2*)kg + (size_t)b * NKEY;
    const int sel = (lane < KSEL) ? (int)myidx : 0;
    const float2 kc = kp[sel];
    const float score = fmaf(A, kc.x, fmaf(Bb, kc.y, Cc));
    float mx = score;
#pragma unroll
    for (int off = 8; off; off >>= 1) mx = fmaxf(mx, __shfl_xor(mx, off));
    const float e = __expf(score - mx);
    float sum = e;
#pragma unroll
    for (int off = 8; off; off >>= 1) sum += __shfl_xor(sum, off);
    const float w = e / sum;                        /* valid lanes 0..15 */

    const float* vb = vg + (size_t)b * NKEY * CV;
    float acc = 0.f;
#pragma unroll
    for (int sct = 0; sct < KSEL; ++sct) {
        const u32 id   = (u32)__builtin_amdgcn_readlane((int)myidx, sct);
        const float ws = __uint_as_float(
            (u32)__builtin_amdgcn_readlane((int)__float_as_uint(w), sct));
        acc = fmaf(ws, vb[(size_t)id * CV + lane], acc);
    }
    outg[((size_t)b * NQ + qi) * CV + lane] = acc;
}

extern "C" void kernel_launch(void* const* d_in, const int* in_sizes, int n_in,
                              void* d_out, int out_size, void* d_ws, size_t ws_size,
                              hipStream_t stream) {
    const float* q  = (const float*)d_in[0];
    const float* k  = (const float*)d_in[1];
    const float* v  = (const float*)d_in[2];
    const float* qw = (const float*)d_in[3];
    const float* qb = (const float*)d_in[4];
    const float* kw = (const float*)d_in[5];
    const float* kb = (const float*)d_in[6];
    /* d_in[7] = top_k (always 16; compile-time) */
    float* out = (float*)d_out;

    float*  w9 = (float*)d_ws;
    u32*    bs = (u32*)((char*)d_ws + WS_BS);
    float2* sx = (float2*)((char*)d_ws + WS_SX);
    u16*    si = (u16*)((char*)d_ws + WS_SI);

    hipLaunchKernelGGL(k_setup, dim3(NB), dim3(1024), 0, stream,
                       k, qw, qb, kw, kb, bs, sx, si, w9);
    hipLaunchKernelGGL(bev_knn, dim3(NB * NQ / 4), dim3(256), 0, stream,
                       q, k, v, w9, bs, sx, si, out);
}

// Round 13
// 64.961 us; speedup vs baseline: 2.4902x; 1.5022x over previous
//
#include <hip/hip_runtime.h>
#include <stdint.h>

typedef uint64_t u64;
typedef uint32_t u32;

#define NB    8
#define NQ    4096
#define NKEY  4096
#define CV    64
#define KSEL  16
#define G     4              /* queries per wave */
#define NWAVE 2              /* waves per block */
#define BLK   (NWAVE * 64)   /* 128 threads */
#define QPB   (G * NWAVE)    /* 8 queries per block */
#define CMAX  64             /* candidate slots per query */
#define PADU  (~(u64)0)

__device__ __forceinline__ u64 shflxor_u64(u64 v, int m) {
    const u32 lo = __shfl_xor((int)(u32)v, m);
    const u32 hi = __shfl_xor((int)(u32)(v >> 32), m);
    return (((u64)hi) << 32) | lo;
}
__device__ __forceinline__ int mbcnt64(u64 m) {
    return (int)__builtin_amdgcn_mbcnt_hi((u32)(m >> 32),
               __builtin_amdgcn_mbcnt_lo((u32)m, 0));
}
/* monotone float -> u32 key (metric k2-2q.k can be negative) */
__device__ __forceinline__ u32 fkey(float f) {
    const u32 b = __float_as_uint(f);
    return b ^ (0x80000000u | (u32)((int32_t)b >> 31));
}
__device__ __forceinline__ void ce64(u64& v, u64 p, bool keepmin) {
    const u64 mn = v < p ? v : p, mx = v < p ? p : v;
    v = keepmin ? mn : mx;
}

/* 2-way interleaved EXACT smallest-16-of-64 selection network.
   Same stage pattern as the R9-proven top16of64; two independent chains
   issue together so the ds_swizzle latency overlaps. */
__device__ __forceinline__ void top16of64x2(u64& a, u64& b, int lane) {
#pragma unroll
    for (int k = 2; k <= 16; k <<= 1) {
#pragma unroll
        for (int j = k >> 1; j > 0; j >>= 1) {
            const bool keepmin = (((lane & j) == 0) == ((lane & k) == 0));
            const u64 pa = shflxor_u64(a, j);
            const u64 pb = shflxor_u64(b, j);
            ce64(a, pa, keepmin); ce64(b, pb, keepmin);
        }
    }
    {   const bool keepmin = ((lane & 16) == 0);
        const u64 pa = shflxor_u64(a, 16);
        const u64 pb = shflxor_u64(b, 16);
        ce64(a, pa, keepmin); ce64(b, pb, keepmin); }
#pragma unroll
    for (int j = 8; j > 0; j >>= 1) {
        const bool keepmin = (((lane & j) == 0) == ((lane & 32) == 0));
        const u64 pa = shflxor_u64(a, j);
        const u64 pb = shflxor_u64(b, j);
        ce64(a, pa, keepmin); ce64(b, pb, keepmin);
    }
    {   const bool keepmin = ((lane & 32) == 0);
        const u64 pa = shflxor_u64(a, 32);
        const u64 pb = shflxor_u64(b, 32);
        ce64(a, pa, keepmin); ce64(b, pb, keepmin); }
}

/* cold overflow fallback (~never; one code copy, uniform branch) */
__device__ __noinline__ int exact_recollect(const float4* __restrict__ kp4,
                                            int lane, float m2xq, float m2yq,
                                            u64* __restrict__ row) {
    u32 lo = 0, hi = ~0u;
#pragma unroll 1
    while (lo < hi) {
        const u32 mid = lo + ((hi - lo) >> 1);
        int cc = 0;
#pragma unroll 1
        for (int c = 0; c < 32; ++c) {
            const float4 kk = kp4[c * 64 + lane];
            const float k2a = fmaf(kk.x, kk.x, kk.y * kk.y);
            const float k2b = fmaf(kk.z, kk.z, kk.w * kk.w);
            const float va = fmaf(kk.x, m2xq, fmaf(kk.y, m2yq, k2a));
            const float vb = fmaf(kk.z, m2xq, fmaf(kk.w, m2yq, k2b));
            cc += (fkey(va) <= mid) ? 1 : 0;
            cc += (fkey(vb) <= mid) ? 1 : 0;
        }
#pragma unroll 1
        for (int off = 32; off; off >>= 1) cc += __shfl_xor(cc, off);
        if (cc >= KSEL) hi = mid; else lo = mid + 1;
    }
    int cc = 0;
#pragma unroll 1
    for (int c = 0; c < 32; ++c) {
        const float4 kk = kp4[c * 64 + lane];
        const float k2a = fmaf(kk.x, kk.x, kk.y * kk.y);
        const float k2b = fmaf(kk.z, kk.z, kk.w * kk.w);
        const float va = fmaf(kk.x, m2xq, fmaf(kk.y, m2yq, k2a));
        const float vb = fmaf(kk.z, m2xq, fmaf(kk.w, m2yq, k2b));
        const u32 ta = fkey(va), tb = fkey(vb);
        const bool aa = ta <= lo, ab = tb <= lo;
        const u64 mka = __ballot(aa);
        const u64 mkb = __ballot(ab);
        const int posa = cc + mbcnt64(mka);
        cc += (int)__popcll(mka);
        const int posb = cc + mbcnt64(mkb);
        cc += (int)__popcll(mkb);
        const u32 ia = (u32)(2 * (c * 64 + lane));
        if (aa && posa < CMAX) row[posa] = (((u64)ta) << 32) | ia;
        if (ab && posb < CMAX) row[posb] = (((u64)tb) << 32) | (ia + 1);
    }
    return cc < CMAX ? cc : CMAX;
}

/* setup: 9 query-independent affine sums over H=64 -> d_ws */
__global__ void setup_kernel(const float* __restrict__ qw, const float* __restrict__ qb,
                             const float* __restrict__ kw, const float* __restrict__ kb,
                             float* __restrict__ w9)
{
    const int h = threadIdx.x & 63;
    const float2 a = ((const float2*)qw)[h];
    const float2 c = ((const float2*)kw)[h];
    const float qbh = qb[h], kbh = kb[h];
    float s[9] = { a.x * c.x, a.y * c.x, qbh * c.x,
                   a.x * c.y, a.y * c.y, qbh * c.y,
                   a.x * kbh, a.y * kbh, qbh * kbh };
#pragma unroll
    for (int i = 0; i < 9; ++i)
#pragma unroll
        for (int off = 32; off; off >>= 1) s[i] += __shfl_xor(s[i], off);
    if (h == 0) {
#pragma unroll
        for (int i = 0; i < 9; ++i) w9[i] = s[i];
    }
}

extern "C" __global__ __launch_bounds__(BLK, 8) void bev_main(
    const float* __restrict__ qg, const float* __restrict__ kg,
    const float* __restrict__ vg, const float* __restrict__ w9,
    float* __restrict__ outg)
{
    __shared__ u64 cand[NWAVE][G][CMAX];      /* 4 KB; per-wave private */

    const int tid  = threadIdx.x;
    const int wv   = tid >> 6;
    const int lane = tid & 63;
    const int wvu  = __builtin_amdgcn_readfirstlane(wv);
    const int b    = blockIdx.x >> 9;                  /* 512 blocks per batch */
    const int qbase = ((int)(blockIdx.x & 511) * NWAVE + wvu) * G;

    const float2* kp  = (const float2*)(kg + (size_t)b * NKEY * 2);
    const float4* kp4 = (const float4*)kp;             /* 2 keys / 16 B */
    const float2* qp  = (const float2*)qg + (size_t)b * NQ + qbase;

    float m2x[G], m2y[G];
#pragma unroll
    for (int q = 0; q < G; ++q) {
        const float2 qc = qp[q];
        m2x[q] = -2.f * qc.x; m2y[q] = -2.f * qc.y;
    }

    /* ---- pass 1: per-lane metric-min per query (shared key loads) ---- */
    float mn[G];
#pragma unroll
    for (int q = 0; q < G; ++q) mn[q] = __builtin_inff();
#pragma unroll 8
    for (int c = 0; c < 32; ++c) {
        const float4 kk = kp4[c * 64 + lane];
        const float k2a = fmaf(kk.x, kk.x, kk.y * kk.y);
        const float k2b = fmaf(kk.z, kk.z, kk.w * kk.w);
#pragma unroll
        for (int q = 0; q < G; ++q) {
            const float va = fmaf(kk.x, m2x[q], fmaf(kk.y, m2y[q], k2a));
            const float vb = fmaf(kk.z, m2x[q], fmaf(kk.w, m2y[q], k2b));
            mn[q] = fminf(fminf(va, vb), mn[q]);
        }
    }

    /* ---- thresholds: 16th-smallest of 64 lane-mins.
       4-way stage-major interleave: one 21-stage chain instead of four. ---- */
    float thr[G];
    {
        float v0 = mn[0], v1 = mn[1], v2 = mn[2], v3 = mn[3];
#pragma unroll
        for (int k = 2; k <= 64; k <<= 1) {
#pragma unroll
            for (int j = k >> 1; j > 0; j >>= 1) {
                const bool keepmin = (((lane & j) == 0) == ((lane & k) == 0));
                const float p0 = __shfl_xor(v0, j);
                const float p1 = __shfl_xor(v1, j);
                const float p2 = __shfl_xor(v2, j);
                const float p3 = __shfl_xor(v3, j);
                v0 = keepmin ? fminf(v0, p0) : fmaxf(v0, p0);
                v1 = keepmin ? fminf(v1, p1) : fmaxf(v1, p1);
                v2 = keepmin ? fminf(v2, p2) : fmaxf(v2, p2);
                v3 = keepmin ? fminf(v3, p3) : fmaxf(v3, p3);
            }
        }
        thr[0] = __shfl(v0, 15); thr[1] = __shfl(v1, 15);
        thr[2] = __shfl(v2, 15); thr[3] = __shfl(v3, 15);
    }

    /* ---- pass 2: recompute metric, ballot-append all <= thr ---- */
    int cnt[G];
#pragma unroll
    for (int q = 0; q < G; ++q) cnt[q] = 0;
#pragma unroll 4
    for (int c = 0; c < 32; ++c) {
        const float4 kk = kp4[c * 64 + lane];
        const float k2a = fmaf(kk.x, kk.x, kk.y * kk.y);
        const float k2b = fmaf(kk.z, kk.z, kk.w * kk.w);
        const u32 ia = (u32)(2 * (c * 64 + lane));
#pragma unroll
        for (int q = 0; q < G; ++q) {
            const float va = fmaf(kk.x, m2x[q], fmaf(kk.y, m2y[q], k2a));
            const float vb = fmaf(kk.z, m2x[q], fmaf(kk.w, m2y[q], k2b));
            const bool aa = va <= thr[q];
            const bool ab = vb <= thr[q];
            const u64 mka = __ballot(aa);
            const u64 mkb = __ballot(ab);
            if (mka | mkb) {                           /* uniform branch */
                const int posa = cnt[q] + mbcnt64(mka);
                cnt[q] += (int)__popcll(mka);
                const int posb = cnt[q] + mbcnt64(mkb);
                cnt[q] += (int)__popcll(mkb);
                if (aa && posa < CMAX)
                    cand[wv][q][posa] = (((u64)fkey(va)) << 32) | ia;
                if (ab && posb < CMAX)
                    cand[wv][q][posb] = (((u64)fkey(vb)) << 32) | (ia + 1);
            }
        }
    }

    /* ---- overflow fallback (~never) ---- */
#pragma unroll
    for (int q = 0; q < G; ++q) {
        if (cnt[q] > CMAX) {
            const float2 qc = qp[q];
            cnt[q] = exact_recollect(kp4, lane, -2.f * qc.x, -2.f * qc.y,
                                     &cand[wv][q][0]);
        }
    }

    /* ---- epilogue: query PAIRS, fully unrolled, chains interleaved ---- */
    const float s1 = w9[0], s2 = w9[1], s3 = w9[2];
    const float s4 = w9[3], s5 = w9[4], s6 = w9[5];
    const float s7 = w9[6], s8 = w9[7], s9 = w9[8];
    const float* vb = vg + (size_t)b * NKEY * CV;

#pragma unroll
    for (int pr = 0; pr < G / 2; ++pr) {
        const int qa = 2 * pr, qb2 = 2 * pr + 1;

        u64 mya = (lane < cnt[qa])  ? cand[wv][qa][lane]  : PADU;
        u64 myb = (lane < cnt[qb2]) ? cand[wv][qb2][lane] : PADU;
        top16of64x2(mya, myb, lane);
        const u32 idxa = (u32)mya, idxb = (u32)myb;

        const float2 qca = qp[qa], qcb = qp[qb2];
        const float Aa  = fmaf(qca.x, s1, fmaf(qca.y, s2, s3));
        const float Ba  = fmaf(qca.x, s4, fmaf(qca.y, s5, s6));
        const float Ca  = fmaf(qca.x, s7, fmaf(qca.y, s8, s9));
        const float Ab  = fmaf(qcb.x, s1, fmaf(qcb.y, s2, s3));
        const float Bbb = fmaf(qcb.x, s4, fmaf(qcb.y, s5, s6));
        const float Cb  = fmaf(qcb.x, s7, fmaf(qcb.y, s8, s9));

        const int sela = (lane < KSEL) ? (int)idxa : 0;
        const int selb = (lane < KSEL) ? (int)idxb : 0;
        const float2 kca = kp[sela];
        const float2 kcb = kp[selb];
        const float sca = fmaf(Aa, kca.x, fmaf(Ba,  kca.y, Ca));
        const float scb = fmaf(Ab, kcb.x, fmaf(Bbb, kcb.y, Cb));

        float mxa = sca, mxb = scb;
#pragma unroll
        for (int off = 8; off; off >>= 1) {
            mxa = fmaxf(mxa, __shfl_xor(mxa, off));
            mxb = fmaxf(mxb, __shfl_xor(mxb, off));
        }
        const float ea = __expf(sca - mxa);
        const float eb = __expf(scb - mxb);
        float sua = ea, sub = eb;
#pragma unroll
        for (int off = 8; off; off >>= 1) {
            sua += __shfl_xor(sua, off);
            sub += __shfl_xor(sub, off);
        }
        const float wa = ea / sua;                    /* valid lanes 0..15 */
        const float wb = eb / sub;

        float acca = 0.f, accb = 0.f;
#pragma unroll
        for (int s = 0; s < KSEL; ++s) {
            const u32 ida = (u32)__builtin_amdgcn_readlane((int)idxa, s);
            const u32 idb = (u32)__builtin_amdgcn_readlane((int)idxb, s);
            const float wsa = __uint_as_float(
                (u32)__builtin_amdgcn_readlane((int)__float_as_uint(wa), s));
            const float wsb = __uint_as_float(
                (u32)__builtin_amdgcn_readlane((int)__float_as_uint(wb), s));
            acca = fmaf(wsa, vb[(size_t)ida * CV + lane], acca);
            accb = fmaf(wsb, vb[(size_t)idb * CV + lane], accb);
        }
        outg[((size_t)b * NQ + qbase + qa)  * CV + lane] = acca;
        outg[((size_t)b * NQ + qbase + qb2) * CV + lane] = accb;
    }
}

extern "C" void kernel_launch(void* const* d_in, const int* in_sizes, int n_in,
                              void* d_out, int out_size, void* d_ws, size_t ws_size,
                              hipStream_t stream) {
    const float* q  = (const float*)d_in[0];
    const float* k  = (const float*)d_in[1];
    const float* v  = (const float*)d_in[2];
    const float* qw = (const float*)d_in[3];
    const float* qb = (const float*)d_in[4];
    const float* kw = (const float*)d_in[5];
    const float* kb = (const float*)d_in[6];
    /* d_in[7] = top_k (always 16; compile-time) */
    float* out = (float*)d_out;
    float* w9  = (float*)d_ws;

    hipLaunchKernelGGL(setup_kernel, dim3(1), dim3(64), 0, stream,
                       qw, qb, kw, kb, w9);
    hipLaunchKernelGGL(bev_main, dim3(NB * NQ / QPB), dim3(BLK),
                       0, stream, q, k, v, w9, out);
}

// Round 14
// 63.823 us; speedup vs baseline: 2.5345x; 1.0178x over previous
//
#include <hip/hip_runtime.h>
#include <stdint.h>

typedef uint64_t u64;
typedef uint32_t u32;

#define NB    8
#define NQ    4096
#define NKEY  4096
#define CV    64
#define KSEL  16
#define G     4              /* queries per wave */
#define NWAVE 2              /* waves per block */
#define BLK   (NWAVE * 64)   /* 128 threads */
#define QPB   (G * NWAVE)    /* 8 queries per block */
#define CMAX  64             /* logical candidate limit per query */
#define CPAD  80             /* padded row: unguarded append, clamped addr */
#define PADU  (~(u64)0)

__device__ __forceinline__ u64 shflxor_u64(u64 v, int m) {
    const u32 lo = __shfl_xor((int)(u32)v, m);
    const u32 hi = __shfl_xor((int)(u32)(v >> 32), m);
    return (((u64)hi) << 32) | lo;
}
__device__ __forceinline__ int mbcnt64(u64 m) {
    return (int)__builtin_amdgcn_mbcnt_hi((u32)(m >> 32),
               __builtin_amdgcn_mbcnt_lo((u32)m, 0));
}
/* monotone float -> u32 key (metric k2-2q.k can be negative) */
__device__ __forceinline__ u32 fkey(float f) {
    const u32 b = __float_as_uint(f);
    return b ^ (0x80000000u | (u32)((int32_t)b >> 31));
}
__device__ __forceinline__ void ce64(u64& v, u64 p, bool keepmin) {
    const u64 mn = v < p ? v : p, mx = v < p ? p : v;
    v = keepmin ? mn : mx;
}

/* 2-way interleaved EXACT smallest-16-of-64 selection network (R13-proven) */
__device__ __forceinline__ void top16of64x2(u64& a, u64& b, int lane) {
#pragma unroll
    for (int k = 2; k <= 16; k <<= 1) {
#pragma unroll
        for (int j = k >> 1; j > 0; j >>= 1) {
            const bool keepmin = (((lane & j) == 0) == ((lane & k) == 0));
            const u64 pa = shflxor_u64(a, j);
            const u64 pb = shflxor_u64(b, j);
            ce64(a, pa, keepmin); ce64(b, pb, keepmin);
        }
    }
    {   const bool keepmin = ((lane & 16) == 0);
        const u64 pa = shflxor_u64(a, 16);
        const u64 pb = shflxor_u64(b, 16);
        ce64(a, pa, keepmin); ce64(b, pb, keepmin); }
#pragma unroll
    for (int j = 8; j > 0; j >>= 1) {
        const bool keepmin = (((lane & j) == 0) == ((lane & 32) == 0));
        const u64 pa = shflxor_u64(a, j);
        const u64 pb = shflxor_u64(b, j);
        ce64(a, pa, keepmin); ce64(b, pb, keepmin);
    }
    {   const bool keepmin = ((lane & 32) == 0);
        const u64 pa = shflxor_u64(a, 32);
        const u64 pb = shflxor_u64(b, 32);
        ce64(a, pa, keepmin); ce64(b, pb, keepmin); }
}

/* cold overflow fallback (~never; one code copy, uniform branch) */
__device__ __noinline__ int exact_recollect(const float4* __restrict__ kp4,
                                            int lane, float m2xq, float m2yq,
                                            u64* __restrict__ row) {
    u32 lo = 0, hi = ~0u;
#pragma unroll 1
    while (lo < hi) {
        const u32 mid = lo + ((hi - lo) >> 1);
        int cc = 0;
#pragma unroll 1
        for (int c = 0; c < 32; ++c) {
            const float4 kk = kp4[c * 64 + lane];
            const float k2a = fmaf(kk.x, kk.x, kk.y * kk.y);
            const float k2b = fmaf(kk.z, kk.z, kk.w * kk.w);
            const float va = fmaf(kk.x, m2xq, fmaf(kk.y, m2yq, k2a));
            const float vb = fmaf(kk.z, m2xq, fmaf(kk.w, m2yq, k2b));
            cc += (fkey(va) <= mid) ? 1 : 0;
            cc += (fkey(vb) <= mid) ? 1 : 0;
        }
#pragma unroll 1
        for (int off = 32; off; off >>= 1) cc += __shfl_xor(cc, off);
        if (cc >= KSEL) hi = mid; else lo = mid + 1;
    }
    int cc = 0;
#pragma unroll 1
    for (int c = 0; c < 32; ++c) {
        const float4 kk = kp4[c * 64 + lane];
        const float k2a = fmaf(kk.x, kk.x, kk.y * kk.y);
        const float k2b = fmaf(kk.z, kk.z, kk.w * kk.w);
        const float va = fmaf(kk.x, m2xq, fmaf(kk.y, m2yq, k2a));
        const float vb = fmaf(kk.z, m2xq, fmaf(kk.w, m2yq, k2b));
        const u32 ta = fkey(va), tb = fkey(vb);
        const bool aa = ta <= lo, ab = tb <= lo;
        const u64 mka = __ballot(aa);
        const u64 mkb = __ballot(ab);
        const int posa = cc + mbcnt64(mka);
        cc += (int)__popcll(mka);
        const int posb = cc + mbcnt64(mkb);
        cc += (int)__popcll(mkb);
        const u32 ia = (u32)(2 * (c * 64 + lane));
        if (aa && posa < CMAX) row[posa] = (((u64)ta) << 32) | ia;
        if (ab && posb < CMAX) row[posb] = (((u64)tb) << 32) | (ia + 1);
    }
    return cc < CMAX ? cc : CMAX;
}

/* setup: 9 query-independent affine sums over H=64 -> d_ws */
__global__ void setup_kernel(const float* __restrict__ qw, const float* __restrict__ qb,
                             const float* __restrict__ kw, const float* __restrict__ kb,
                             float* __restrict__ w9)
{
    const int h = threadIdx.x & 63;
    const float2 a = ((const float2*)qw)[h];
    const float2 c = ((const float2*)kw)[h];
    const float qbh = qb[h], kbh = kb[h];
    float s[9] = { a.x * c.x, a.y * c.x, qbh * c.x,
                   a.x * c.y, a.y * c.y, qbh * c.y,
                   a.x * kbh, a.y * kbh, qbh * kbh };
#pragma unroll
    for (int i = 0; i < 9; ++i)
#pragma unroll
        for (int off = 32; off; off >>= 1) s[i] += __shfl_xor(s[i], off);
    if (h == 0) {
#pragma unroll
        for (int i = 0; i < 9; ++i) w9[i] = s[i];
    }
}

extern "C" __global__ __launch_bounds__(BLK, 6) void bev_main(
    const float* __restrict__ qg, const float* __restrict__ kg,
    const float* __restrict__ vg, const float* __restrict__ w9,
    float* __restrict__ outg)
{
    __shared__ u64 cand[NWAVE][G][CPAD];      /* 5 KB; per-wave private */

    const int tid  = threadIdx.x;
    const int wv   = tid >> 6;
    const int lane = tid & 63;
    const int wvu  = __builtin_amdgcn_readfirstlane(wv);
    const int b    = blockIdx.x >> 9;                  /* 512 blocks per batch */
    const int qbase = ((int)(blockIdx.x & 511) * NWAVE + wvu) * G;

    const float2* kp  = (const float2*)(kg + (size_t)b * NKEY * 2);
    const float4* kp4 = (const float4*)kp;             /* 2 keys / 16 B */
    const float2* qp  = (const float2*)qg + (size_t)b * NQ + qbase;

    float m2x[G], m2y[G];
#pragma unroll
    for (int q = 0; q < G; ++q) {
        const float2 qc = qp[q];
        m2x[q] = -2.f * qc.x; m2y[q] = -2.f * qc.y;
    }

    /* ---- pass 1: per-lane metric-min per query (shared key loads) ---- */
    float mn[G];
#pragma unroll
    for (int q = 0; q < G; ++q) mn[q] = __builtin_inff();
#pragma unroll 8
    for (int c = 0; c < 32; ++c) {
        const float4 kk = kp4[c * 64 + lane];
        const float k2a = fmaf(kk.x, kk.x, kk.y * kk.y);
        const float k2b = fmaf(kk.z, kk.z, kk.w * kk.w);
#pragma unroll
        for (int q = 0; q < G; ++q) {
            const float va = fmaf(kk.x, m2x[q], fmaf(kk.y, m2y[q], k2a));
            const float vb = fmaf(kk.z, m2x[q], fmaf(kk.w, m2y[q], k2b));
            mn[q] = fminf(fminf(va, vb), mn[q]);       /* min3-fusable */
        }
    }

    /* ---- thresholds: 16th-smallest of 64 lane-mins (4-way interleaved) ---- */
    float thr[G];
    {
        float v0 = mn[0], v1 = mn[1], v2 = mn[2], v3 = mn[3];
#pragma unroll
        for (int k = 2; k <= 64; k <<= 1) {
#pragma unroll
            for (int j = k >> 1; j > 0; j >>= 1) {
                const bool keepmin = (((lane & j) == 0) == ((lane & k) == 0));
                const float p0 = __shfl_xor(v0, j);
                const float p1 = __shfl_xor(v1, j);
                const float p2 = __shfl_xor(v2, j);
                const float p3 = __shfl_xor(v3, j);
                v0 = keepmin ? fminf(v0, p0) : fmaxf(v0, p0);
                v1 = keepmin ? fminf(v1, p1) : fmaxf(v1, p1);
                v2 = keepmin ? fminf(v2, p2) : fmaxf(v2, p2);
                v3 = keepmin ? fminf(v3, p3) : fmaxf(v3, p3);
            }
        }
        thr[0] = __shfl(v0, 15); thr[1] = __shfl(v1, 15);
        thr[2] = __shfl(v2, 15); thr[3] = __shfl(v3, 15);
    }

    /* ---- pass 2: recompute metric, unguarded ballot-append (clamped addr) ---- */
    int cnt[G];
#pragma unroll
    for (int q = 0; q < G; ++q) cnt[q] = 0;
#pragma unroll 4
    for (int c = 0; c < 32; ++c) {
        const float4 kk = kp4[c * 64 + lane];
        const float k2a = fmaf(kk.x, kk.x, kk.y * kk.y);
        const float k2b = fmaf(kk.z, kk.z, kk.w * kk.w);
        const u32 ia = (u32)(2 * (c * 64 + lane));
#pragma unroll
        for (int q = 0; q < G; ++q) {
            const float va = fmaf(kk.x, m2x[q], fmaf(kk.y, m2y[q], k2a));
            const float vb = fmaf(kk.z, m2x[q], fmaf(kk.w, m2y[q], k2b));
            const bool aa = va <= thr[q];
            const bool ab = vb <= thr[q];
            const u64 mka = __ballot(aa);
            const u64 mkb = __ballot(ab);
            if (mka | mkb) {                           /* uniform branch */
                const int posa = cnt[q] + mbcnt64(mka);
                cnt[q] += (int)__popcll(mka);
                const int posb = cnt[q] + mbcnt64(mkb);
                cnt[q] += (int)__popcll(mkb);
                if (aa)
                    cand[wv][q][posa < CPAD - 1 ? posa : CPAD - 1] =
                        (((u64)fkey(va)) << 32) | ia;
                if (ab)
                    cand[wv][q][posb < CPAD - 1 ? posb : CPAD - 1] =
                        (((u64)fkey(vb)) << 32) | (ia + 1);
            }
        }
    }

    /* ---- overflow fallback (~never; overwrite clobbered row exactly) ---- */
#pragma unroll
    for (int q = 0; q < G; ++q) {
        if (cnt[q] > CMAX) {
            const float2 qc = qp[q];
            cnt[q] = exact_recollect(kp4, lane, -2.f * qc.x, -2.f * qc.y,
                                     &cand[wv][q][0]);
        }
    }

    /* ---- epilogue: query pairs, fully unrolled, chains interleaved ---- */
    const float s1 = w9[0], s2 = w9[1], s3 = w9[2];
    const float s4 = w9[3], s5 = w9[4], s6 = w9[5];
    const float s7 = w9[6], s8 = w9[7], s9 = w9[8];
    const float* vb = vg + (size_t)b * NKEY * CV;

#pragma unroll
    for (int pr = 0; pr < G / 2; ++pr) {
        const int qa = 2 * pr, qb2 = 2 * pr + 1;

        u64 mya = (lane < cnt[qa])  ? cand[wv][qa][lane]  : PADU;
        u64 myb = (lane < cnt[qb2]) ? cand[wv][qb2][lane] : PADU;
        top16of64x2(mya, myb, lane);
        const u32 idxa = (u32)mya, idxb = (u32)myb;

        const float2 qca = qp[qa], qcb = qp[qb2];
        const float Aa  = fmaf(qca.x, s1, fmaf(qca.y, s2, s3));
        const float Ba  = fmaf(qca.x, s4, fmaf(qca.y, s5, s6));
        const float Ca  = fmaf(qca.x, s7, fmaf(qca.y, s8, s9));
        const float Ab  = fmaf(qcb.x, s1, fmaf(qcb.y, s2, s3));
        const float Bbb = fmaf(qcb.x, s4, fmaf(qcb.y, s5, s6));
        const float Cb  = fmaf(qcb.x, s7, fmaf(qcb.y, s8, s9));

        const int sela = (lane < KSEL) ? (int)idxa : 0;
        const int selb = (lane < KSEL) ? (int)idxb : 0;
        const float2 kca = kp[sela];
        const float2 kcb = kp[selb];
        const float sca = fmaf(Aa, kca.x, fmaf(Ba,  kca.y, Ca));
        const float scb = fmaf(Ab, kcb.x, fmaf(Bbb, kcb.y, Cb));

        float mxa = sca, mxb = scb;
#pragma unroll
        for (int off = 8; off; off >>= 1) {
            mxa = fmaxf(mxa, __shfl_xor(mxa, off));
            mxb = fmaxf(mxb, __shfl_xor(mxb, off));
        }
        const float ea = __expf(sca - mxa);
        const float eb = __expf(scb - mxb);
        float sua = ea, sub = eb;
#pragma unroll
        for (int off = 8; off; off >>= 1) {
            sua += __shfl_xor(sua, off);
            sub += __shfl_xor(sub, off);
        }
        const float wa = ea / sua;                    /* valid lanes 0..15 */
        const float wb = eb / sub;

        float acca = 0.f, accb = 0.f;
#pragma unroll
        for (int s = 0; s < KSEL; ++s) {
            const u32 ida = (u32)__builtin_amdgcn_readlane((int)idxa, s);
            const u32 idb = (u32)__builtin_amdgcn_readlane((int)idxb, s);
            const float wsa = __uint_as_float(
                (u32)__builtin_amdgcn_readlane((int)__float_as_uint(wa), s));
            const float wsb = __uint_as_float(
                (u32)__builtin_amdgcn_readlane((int)__float_as_uint(wb), s));
            acca = fmaf(wsa, vb[(size_t)ida * CV + lane], acca);
            accb = fmaf(wsb, vb[(size_t)idb * CV + lane], accb);
        }
        outg[((size_t)b * NQ + qbase + qa)  * CV + lane] = acca;
        outg[((size_t)b * NQ + qbase + qb2) * CV + lane] = accb;
    }
}

extern "C" void kernel_launch(void* const* d_in, const int* in_sizes, int n_in,
                              void* d_out, int out_size, void* d_ws, size_t ws_size,
                              hipStream_t stream) {
    const float* q  = (const float*)d_in[0];
    const float* k  = (const float*)d_in[1];
    const float* v  = (const float*)d_in[2];
    const float* qw = (const float*)d_in[3];
    const float* qb = (const float*)d_in[4];
    const float* kw = (const float*)d_in[5];
    const float* kb = (const float*)d_in[6];
    /* d_in[7] = top_k (always 16; compile-time) */
    float* out = (float*)d_out;
    float* w9  = (float*)d_ws;

    hipLaunchKernelGGL(setup_kernel, dim3(1), dim3(64), 0, stream,
                       qw, qb, kw, kb, w9);
    hipLaunchKernelGGL(bev_main, dim3(NB * NQ / QPB), dim3(BLK),
                       0, stream, q, k, v, w9, out);
}